// Round 1
// baseline (338.309 us; speedup 1.0000x reference)
//
#include <hip/hip_runtime.h>

// SGP spatial encoder: out[n] = concat(x, A x, A^2 x, A^3 x, mean(x)) with
// A = D^-1/2 W D^-1/2 (in-degree at col/target).
// R6: prop was latency-bound (~5 B/cyc/CU gather rate, 2 loads in flight).
// Chunk-8 edge loop: preload slots -> 8 independent gathers in flight.
// Fused dispatches: (fill|colsum), (deginv|init). 6 dispatches total.
// R7: k_build was atomic-serialization bound (78us, 1% VALU, 11% HBM):
// dense cnt[N] packs 16 counters/line -> ~256 device-scope atomics per line
// serialize at the coherent point. Pad cnt to 1 counter per 64B line (CSTR=16).

#define D 128
#define OUTC4 160   // float4s per output row
#define CAP 64      // slots per node; Poisson(16) => overflow ~impossible (guarded)
#define CH 8        // edge chunk = gathers in flight per thread
#define CSTR 16     // cnt stride in ints: one counter per 64B cacheline

__device__ inline unsigned short f2bf(float f) {
    unsigned u = __float_as_uint(f);
    u += 0x7FFFu + ((u >> 16) & 1u);   // round-nearest-even
    return (unsigned short)(u >> 16);
}
__device__ inline float bfhi(unsigned u) {           // bf16 in high half
    return __uint_as_float(u & 0xFFFF0000u);
}
__device__ inline float bflo(unsigned u) {           // bf16 in low half
    return __uint_as_float(u << 16);
}
__device__ inline unsigned pack2(float lo, float hi) {
    return ((unsigned)f2bf(hi) << 16) | (unsigned)f2bf(lo);
}
__device__ inline void fma8(float4& a0, float4& a1, float w, uint4 v) {
    a0.x += w * bflo(v.x); a0.y += w * bfhi(v.x);
    a0.z += w * bflo(v.y); a0.w += w * bfhi(v.y);
    a1.x += w * bflo(v.z); a1.y += w * bfhi(v.z);
    a1.z += w * bflo(v.w); a1.w += w * bfhi(v.w);
}

// A: blocks [0,EB) slot-fill (1 atomic/edge); blocks [EB,EB+512) x column sums
__global__ void k_build(const int* __restrict__ row, const int* __restrict__ col,
                        const float* __restrict__ ew, const float* __restrict__ x,
                        int* __restrict__ cnt, unsigned* __restrict__ slots,
                        float* __restrict__ gsum, int E, int N, int EB) {
    __shared__ float sh[128];
    if ((int)blockIdx.x < EB) {
        int e = blockIdx.x * 256 + threadIdx.x;
        if (e >= E) return;
        int c = col[e];
        int p = atomicAdd(&cnt[(size_t)c * CSTR], 1);
        if (p < CAP)
            slots[(size_t)c * CAP + p] = ((unsigned)f2bf(ew[e]) << 16) | (unsigned)row[e];
    } else {
        int bid = blockIdx.x - EB;        // 0..511
        int f = threadIdx.x & 127;
        int sub = threadIdx.x >> 7;       // 0/1
        float acc = 0.f;
        for (int n = bid * 2 + sub; n < N; n += 1024)
            acc += x[(size_t)n * D + f];
        if (sub) sh[f] = acc;
        __syncthreads();
        if (!sub) atomicAdd(&gsum[f], acc + sh[f]);
    }
}

// B: blocks [0,DB) deginv (wave/node weight-reduce); rest init (x/mean/staging)
__global__ void k_prep(const int* __restrict__ cnt, const unsigned* __restrict__ slots,
                       float* __restrict__ dinv, const float4* __restrict__ x4,
                       const float* __restrict__ gsum, float4* __restrict__ out4,
                       uint4* __restrict__ xb0, int N, int DB, float invN) {
    if ((int)blockIdx.x < DB) {
        int t = blockIdx.x * 256 + threadIdx.x;
        int node = t >> 6;
        int lane = t & 63;
        if (node >= N) return;
        int c = cnt[(size_t)node * CSTR]; if (c > CAP) c = CAP;
        float v = (lane < c) ? bfhi(slots[(size_t)node * CAP + lane]) : 0.f;
        for (int off = 32; off; off >>= 1) v += __shfl_down(v, off, 64);
        if (lane == 0) dinv[node] = v > 0.f ? rsqrtf(v) : 0.f;
    } else {
        int t = (blockIdx.x - DB) * 256 + threadIdx.x;
        if (t >= N * 16) return;
        int n = t >> 4;
        int q = t & 15;
        float4 v0 = x4[(size_t)n * 32 + 2 * q];
        float4 v1 = x4[(size_t)n * 32 + 2 * q + 1];
        size_t ob = (size_t)n * OUTC4;
        out4[ob + 2 * q] = v0;
        out4[ob + 2 * q + 1] = v1;
        xb0[(size_t)n * 16 + q] = make_uint4(pack2(v0.x, v0.y), pack2(v0.z, v0.w),
                                             pack2(v1.x, v1.y), pack2(v1.z, v1.w));
        int g = 8 * q;
        out4[ob + 128 + 2 * q] = make_float4(gsum[g] * invN, gsum[g + 1] * invN,
                                             gsum[g + 2] * invN, gsum[g + 3] * invN);
        out4[ob + 129 + 2 * q] = make_float4(gsum[g + 4] * invN, gsum[g + 5] * invN,
                                             gsum[g + 6] * invN, gsum[g + 7] * invN);
    }
}

// pull hop: 16 lanes/node, lane owns 8 bf16 columns. Chunk-8 edge loop for MLP.
// NORM (hop1): w = dinv[dst]*ew*dinv[src] fp32; slot rewritten as bf16(w).
template <bool NORM>
__global__ void k_prop(const int* __restrict__ cnt, unsigned* __restrict__ slots,
                       const float* __restrict__ dinv, const uint4* __restrict__ xin,
                       float4* __restrict__ out4, uint4* __restrict__ xout,
                       int N, int out_off4, int writeb) {
    int t = blockIdx.x * blockDim.x + threadIdx.x;
    int node = t >> 4;
    if (node >= N) return;
    int lane = t & 15;
    int c = cnt[(size_t)node * CSTR]; if (c > CAP) c = CAP;
    unsigned* s = slots + (size_t)node * CAP;
    float dd = NORM ? dinv[node] : 0.f;
    float4 a0 = make_float4(0.f, 0.f, 0.f, 0.f);
    float4 a1 = make_float4(0.f, 0.f, 0.f, 0.f);
    int i = 0;
    for (; i + CH <= c; i += CH) {
        unsigned sl[CH]; float w[CH]; uint4 v[CH];
#pragma unroll
        for (int j = 0; j < CH; j++) sl[j] = s[i + j];
#pragma unroll
        for (int j = 0; j < CH; j++)
            w[j] = NORM ? dd * bfhi(sl[j]) * dinv[sl[j] & 0xFFFFu] : bfhi(sl[j]);
        if (NORM && lane == 0) {
#pragma unroll
            for (int j = 0; j < CH; j++)
                s[i + j] = ((unsigned)f2bf(w[j]) << 16) | (sl[j] & 0xFFFFu);
        }
#pragma unroll
        for (int j = 0; j < CH; j++) v[j] = xin[(size_t)(sl[j] & 0xFFFFu) * 16 + lane];
#pragma unroll
        for (int j = 0; j < CH; j++) fma8(a0, a1, w[j], v[j]);
    }
    if (i < c) {  // predicated tail chunk; clamped dup addresses are L1-hits
        unsigned sl[CH]; float w[CH]; uint4 v[CH];
#pragma unroll
        for (int j = 0; j < CH; j++) {
            int idx = (i + j < c) ? i + j : c - 1;
            sl[j] = s[idx];
        }
#pragma unroll
        for (int j = 0; j < CH; j++) {
            float ww = NORM ? dd * bfhi(sl[j]) * dinv[sl[j] & 0xFFFFu] : bfhi(sl[j]);
            w[j] = (i + j < c) ? ww : 0.f;
        }
        if (NORM && lane == 0) {
#pragma unroll
            for (int j = 0; j < CH; j++)
                if (i + j < c) s[i + j] = ((unsigned)f2bf(w[j]) << 16) | (sl[j] & 0xFFFFu);
        }
#pragma unroll
        for (int j = 0; j < CH; j++) v[j] = xin[(size_t)(sl[j] & 0xFFFFu) * 16 + lane];
#pragma unroll
        for (int j = 0; j < CH; j++) fma8(a0, a1, w[j], v[j]);
    }
    size_t ob = (size_t)node * OUTC4 + out_off4 + 2 * lane;
    out4[ob] = a0;
    out4[ob + 1] = a1;
    if (writeb)
        xout[(size_t)node * 16 + lane] =
            make_uint4(pack2(a0.x, a0.y), pack2(a0.z, a0.w),
                       pack2(a1.x, a1.y), pack2(a1.z, a1.w));
}

extern "C" void kernel_launch(void* const* d_in, const int* in_sizes, int n_in,
                              void* d_out, int out_size, void* d_ws, size_t ws_size,
                              hipStream_t stream) {
    const float* x = (const float*)d_in[0];
    const int* ei = (const int*)d_in[1];   // int32 per harness convention
    const float* ew = (const float*)d_in[2];
    float* out = (float*)d_out;

    int N = in_sizes[0] / D;
    int E = in_sizes[2];
    const int* row = ei;        // source
    const int* colp = ei + E;   // target

    // ws: [cnt N*CSTR i | gsum 128 f | dinv N f | slots N*CAP u32 | xb0 N*16 uint4 | xb1 ...]
    int* cnt = (int*)d_ws;
    float* gsum = (float*)(cnt + (size_t)N * CSTR);
    float* dinv = gsum + 128;
    unsigned* slots = (unsigned*)(dinv + N);
    uint4* xb0 = (uint4*)(slots + (size_t)N * CAP);
    uint4* xb1 = xb0 + (size_t)N * 16;

    hipMemsetAsync(d_ws, 0, ((size_t)N * CSTR + 128) * sizeof(int), stream);

    int EB = (E + 255) / 256;                    // fill blocks
    k_build<<<EB + 512, 256, 0, stream>>>(row, colp, ew, x, cnt, slots, gsum, E, N, EB);

    int DB = (N * 64 + 255) / 256;               // deginv blocks
    int IB = (N * 16 + 255) / 256;               // init blocks
    k_prep<<<DB + IB, 256, 0, stream>>>(cnt, slots, dinv, (const float4*)x, gsum,
                                        (float4*)out, xb0, N, DB, 1.f / (float)N);

    int pblocks = (N * 16 + 255) / 256;
    // hop1 (fused norm): xb0 -> out[:,128:256] + xb1
    k_prop<true><<<pblocks, 256, 0, stream>>>(cnt, slots, dinv, xb0, (float4*)out, xb1, N, 32, 1);
    // hop2: xb1 -> out[:,256:384] + xb0
    k_prop<false><<<pblocks, 256, 0, stream>>>(cnt, slots, dinv, xb1, (float4*)out, xb0, N, 64, 1);
    // hop3: xb0 -> out[:,384:512]
    k_prop<false><<<pblocks, 256, 0, stream>>>(cnt, slots, dinv, xb0, (float4*)out, xb1, N, 96, 0);
}

// Round 2
// 315.607 us; speedup vs baseline: 1.0719x; 1.0719x over previous
//
#include <hip/hip_runtime.h>

// SGP spatial encoder: out[n] = concat(x, A x, A^2 x, A^3 x, mean(x)) with
// A = D^-1/2 W D^-1/2 (in-degree at col/target).
// R6: prop was latency-bound (~5 B/cyc/CU gather rate, 2 loads in flight).
// Chunk-8 edge loop: preload slots -> 8 independent gathers in flight.
// Fused dispatches: (fill|colsum), (deginv|init). 6 dispatches total.
// R7 FAILED: cnt padding (1 counter/line) left k_build at 77us -> atomics are
// NOT line-collision bound; and strided cnt reads cost +24us downstream. Reverted.
// R8: k_build is latency-chain bound in both phases:
//   fill = 1 serial load->far-atomic->store chain per thread (MLP=1),
//   colsum = 49 sequential HBM-cold loads per block.
// Fix: 4 independent edge chains/thread (EC=4) + ILP-4 colsum accumulators.

#define D 128
#define OUTC4 160   // float4s per output row
#define CAP 64      // slots per node; Poisson(16) => overflow ~impossible (guarded)
#define CH 8        // edge chunk = gathers in flight per thread
#define EC 4        // edge chains per fill thread (atomic MLP)
#define CB 512      // colsum blocks

__device__ inline unsigned short f2bf(float f) {
    unsigned u = __float_as_uint(f);
    u += 0x7FFFu + ((u >> 16) & 1u);   // round-nearest-even
    return (unsigned short)(u >> 16);
}
__device__ inline float bfhi(unsigned u) {           // bf16 in high half
    return __uint_as_float(u & 0xFFFF0000u);
}
__device__ inline float bflo(unsigned u) {           // bf16 in low half
    return __uint_as_float(u << 16);
}
__device__ inline unsigned pack2(float lo, float hi) {
    return ((unsigned)f2bf(hi) << 16) | (unsigned)f2bf(lo);
}
__device__ inline void fma8(float4& a0, float4& a1, float w, uint4 v) {
    a0.x += w * bflo(v.x); a0.y += w * bfhi(v.x);
    a0.z += w * bflo(v.y); a0.w += w * bfhi(v.y);
    a1.x += w * bflo(v.z); a1.y += w * bfhi(v.z);
    a1.z += w * bflo(v.w); a1.w += w * bfhi(v.w);
}

// A: blocks [0,CB) x column sums (ILP-4); blocks [CB,CB+FB) slot-fill (EC chains/thread)
__global__ void k_build(const int* __restrict__ row, const int* __restrict__ col,
                        const float* __restrict__ ew, const float* __restrict__ x,
                        int* __restrict__ cnt, unsigned* __restrict__ slots,
                        float* __restrict__ gsum, int E, int N, int FB) {
    __shared__ float sh[128];
    if ((int)blockIdx.x >= CB) {
        int t = (blockIdx.x - CB) * 256 + threadIdx.x;
        int S = FB * 256;
        int e[EC]; bool ok[EC]; int cc[EC]; unsigned pay[EC];
#pragma unroll
        for (int j = 0; j < EC; j++) {
            e[j] = t + j * S;
            ok[j] = e[j] < E;
            cc[j] = ok[j] ? col[e[j]] : 0;
        }
#pragma unroll
        for (int j = 0; j < EC; j++)
            pay[j] = ok[j] ? (((unsigned)f2bf(ew[e[j]]) << 16) | (unsigned)row[e[j]]) : 0u;
        int p[EC];
#pragma unroll
        for (int j = 0; j < EC; j++)
            if (ok[j]) p[j] = atomicAdd(&cnt[cc[j]], 1);
#pragma unroll
        for (int j = 0; j < EC; j++)
            if (ok[j] && p[j] < CAP) slots[(size_t)cc[j] * CAP + p[j]] = pay[j];
    } else {
        int bid = blockIdx.x;             // 0..CB-1
        int f = threadIdx.x & 127;
        int sub = threadIdx.x >> 7;       // 0/1
        float a0 = 0.f, a1 = 0.f, a2 = 0.f, a3 = 0.f;
        for (int n = bid * 2 + sub; n < N; n += 4 * CB * 2) {
            int n1 = n + CB * 2, n2 = n + 2 * CB * 2, n3 = n + 3 * CB * 2;
            a0 += x[(size_t)n * D + f];
            if (n1 < N) a1 += x[(size_t)n1 * D + f];
            if (n2 < N) a2 += x[(size_t)n2 * D + f];
            if (n3 < N) a3 += x[(size_t)n3 * D + f];
        }
        float acc = (a0 + a1) + (a2 + a3);
        if (sub) sh[f] = acc;
        __syncthreads();
        if (!sub) atomicAdd(&gsum[f], acc + sh[f]);
    }
}

// B: blocks [0,DB) deginv (wave/node weight-reduce); rest init (x/mean/staging)
__global__ void k_prep(const int* __restrict__ cnt, const unsigned* __restrict__ slots,
                       float* __restrict__ dinv, const float4* __restrict__ x4,
                       const float* __restrict__ gsum, float4* __restrict__ out4,
                       uint4* __restrict__ xb0, int N, int DB, float invN) {
    if ((int)blockIdx.x < DB) {
        int t = blockIdx.x * 256 + threadIdx.x;
        int node = t >> 6;
        int lane = t & 63;
        if (node >= N) return;
        int c = cnt[node]; if (c > CAP) c = CAP;
        float v = (lane < c) ? bfhi(slots[(size_t)node * CAP + lane]) : 0.f;
        for (int off = 32; off; off >>= 1) v += __shfl_down(v, off, 64);
        if (lane == 0) dinv[node] = v > 0.f ? rsqrtf(v) : 0.f;
    } else {
        int t = (blockIdx.x - DB) * 256 + threadIdx.x;
        if (t >= N * 16) return;
        int n = t >> 4;
        int q = t & 15;
        float4 v0 = x4[(size_t)n * 32 + 2 * q];
        float4 v1 = x4[(size_t)n * 32 + 2 * q + 1];
        size_t ob = (size_t)n * OUTC4;
        out4[ob + 2 * q] = v0;
        out4[ob + 2 * q + 1] = v1;
        xb0[(size_t)n * 16 + q] = make_uint4(pack2(v0.x, v0.y), pack2(v0.z, v0.w),
                                             pack2(v1.x, v1.y), pack2(v1.z, v1.w));
        int g = 8 * q;
        out4[ob + 128 + 2 * q] = make_float4(gsum[g] * invN, gsum[g + 1] * invN,
                                             gsum[g + 2] * invN, gsum[g + 3] * invN);
        out4[ob + 129 + 2 * q] = make_float4(gsum[g + 4] * invN, gsum[g + 5] * invN,
                                             gsum[g + 6] * invN, gsum[g + 7] * invN);
    }
}

// pull hop: 16 lanes/node, lane owns 8 bf16 columns. Chunk-8 edge loop for MLP.
// NORM (hop1): w = dinv[dst]*ew*dinv[src] fp32; slot rewritten as bf16(w).
template <bool NORM>
__global__ void k_prop(const int* __restrict__ cnt, unsigned* __restrict__ slots,
                       const float* __restrict__ dinv, const uint4* __restrict__ xin,
                       float4* __restrict__ out4, uint4* __restrict__ xout,
                       int N, int out_off4, int writeb) {
    int t = blockIdx.x * blockDim.x + threadIdx.x;
    int node = t >> 4;
    if (node >= N) return;
    int lane = t & 15;
    int c = cnt[node]; if (c > CAP) c = CAP;
    unsigned* s = slots + (size_t)node * CAP;
    float dd = NORM ? dinv[node] : 0.f;
    float4 a0 = make_float4(0.f, 0.f, 0.f, 0.f);
    float4 a1 = make_float4(0.f, 0.f, 0.f, 0.f);
    int i = 0;
    for (; i + CH <= c; i += CH) {
        unsigned sl[CH]; float w[CH]; uint4 v[CH];
#pragma unroll
        for (int j = 0; j < CH; j++) sl[j] = s[i + j];
#pragma unroll
        for (int j = 0; j < CH; j++)
            w[j] = NORM ? dd * bfhi(sl[j]) * dinv[sl[j] & 0xFFFFu] : bfhi(sl[j]);
        if (NORM && lane == 0) {
#pragma unroll
            for (int j = 0; j < CH; j++)
                s[i + j] = ((unsigned)f2bf(w[j]) << 16) | (sl[j] & 0xFFFFu);
        }
#pragma unroll
        for (int j = 0; j < CH; j++) v[j] = xin[(size_t)(sl[j] & 0xFFFFu) * 16 + lane];
#pragma unroll
        for (int j = 0; j < CH; j++) fma8(a0, a1, w[j], v[j]);
    }
    if (i < c) {  // predicated tail chunk; clamped dup addresses are L1-hits
        unsigned sl[CH]; float w[CH]; uint4 v[CH];
#pragma unroll
        for (int j = 0; j < CH; j++) {
            int idx = (i + j < c) ? i + j : c - 1;
            sl[j] = s[idx];
        }
#pragma unroll
        for (int j = 0; j < CH; j++) {
            float ww = NORM ? dd * bfhi(sl[j]) * dinv[sl[j] & 0xFFFFu] : bfhi(sl[j]);
            w[j] = (i + j < c) ? ww : 0.f;
        }
        if (NORM && lane == 0) {
#pragma unroll
            for (int j = 0; j < CH; j++)
                if (i + j < c) s[i + j] = ((unsigned)f2bf(w[j]) << 16) | (sl[j] & 0xFFFFu);
        }
#pragma unroll
        for (int j = 0; j < CH; j++) v[j] = xin[(size_t)(sl[j] & 0xFFFFu) * 16 + lane];
#pragma unroll
        for (int j = 0; j < CH; j++) fma8(a0, a1, w[j], v[j]);
    }
    size_t ob = (size_t)node * OUTC4 + out_off4 + 2 * lane;
    out4[ob] = a0;
    out4[ob + 1] = a1;
    if (writeb)
        xout[(size_t)node * 16 + lane] =
            make_uint4(pack2(a0.x, a0.y), pack2(a0.z, a0.w),
                       pack2(a1.x, a1.y), pack2(a1.z, a1.w));
}

extern "C" void kernel_launch(void* const* d_in, const int* in_sizes, int n_in,
                              void* d_out, int out_size, void* d_ws, size_t ws_size,
                              hipStream_t stream) {
    const float* x = (const float*)d_in[0];
    const int* ei = (const int*)d_in[1];   // int32 per harness convention
    const float* ew = (const float*)d_in[2];
    float* out = (float*)d_out;

    int N = in_sizes[0] / D;
    int E = in_sizes[2];
    const int* row = ei;        // source
    const int* colp = ei + E;   // target

    // ws: [cnt N i | gsum 128 f | dinv N f | slots N*CAP u32 | xb0 N*16 uint4 | xb1 ...]
    int* cnt = (int*)d_ws;
    float* gsum = (float*)(cnt + N);
    float* dinv = gsum + 128;
    unsigned* slots = (unsigned*)(dinv + N);
    uint4* xb0 = (uint4*)(slots + (size_t)N * CAP);
    uint4* xb1 = xb0 + (size_t)N * 16;

    hipMemsetAsync(d_ws, 0, (size_t)(N + 128) * sizeof(int), stream);

    int FB = (E + 256 * EC - 1) / (256 * EC);    // fill blocks (EC edges/thread)
    k_build<<<CB + FB, 256, 0, stream>>>(row, colp, ew, x, cnt, slots, gsum, E, N, FB);

    int DB = (N * 64 + 255) / 256;               // deginv blocks
    int IB = (N * 16 + 255) / 256;               // init blocks
    k_prep<<<DB + IB, 256, 0, stream>>>(cnt, slots, dinv, (const float4*)x, gsum,
                                        (float4*)out, xb0, N, DB, 1.f / (float)N);

    int pblocks = (N * 16 + 255) / 256;
    // hop1 (fused norm): xb0 -> out[:,128:256] + xb1
    k_prop<true><<<pblocks, 256, 0, stream>>>(cnt, slots, dinv, xb0, (float4*)out, xb1, N, 32, 1);
    // hop2: xb1 -> out[:,256:384] + xb0
    k_prop<false><<<pblocks, 256, 0, stream>>>(cnt, slots, dinv, xb1, (float4*)out, xb0, N, 64, 1);
    // hop3: xb0 -> out[:,384:512]
    k_prop<false><<<pblocks, 256, 0, stream>>>(cnt, slots, dinv, xb0, (float4*)out, xb1, N, 96, 0);
}

// Round 3
// 283.822 us; speedup vs baseline: 1.1920x; 1.1120x over previous
//
#include <hip/hip_runtime.h>

// SGP spatial encoder: out[n] = concat(x, A x, A^2 x, A^3 x, mean(x)) with
// A = D^-1/2 W D^-1/2 (in-degree at col/target).
// R6: prop was latency-bound; chunk-8 edge loop -> 8 gathers in flight.
// R7 FAILED: cnt line-padding neutral -> not line-collision bound.
// R8 FAILED: EC=4 atomic chains neutral/worse -> not latency bound.
// => k_build was device-atomic THROUGHPUT bound: 800k returning device-scope
//    atomics / 77us = ~4.3/cycle device-wide service rate at the coherent point.
// R9: two-level bucket partition. Pass1: 256 blocks, LDS histogram over 256
// coarse buckets (col>>8), ONE global atomicAdd per (block,bucket) to reserve
// a chunk (65k atomics, 12x fewer), scatter packed edges into bucket regions.
// Pass2: block-per-bucket grouping with LDS-only atomics; writes slots dense,
// fuses deginv (cnt+dinv computed in-LDS; old slot re-read phase deleted).

#define D 128
#define OUTC4 160   // float4s per output row
#define CAP 64      // slots per node; Poisson(16) => overflow ~impossible (guarded)
#define CH 8        // edge chunk = gathers in flight per thread (prop)
#define PB 256      // partition blocks = coarse buckets
#define CB 512      // colsum blocks
#define BCAP 5120   // bucket capacity (mean 4096, 16 sigma headroom; guarded)

__device__ inline unsigned short f2bf(float f) {
    unsigned u = __float_as_uint(f);
    u += 0x7FFFu + ((u >> 16) & 1u);   // round-nearest-even
    return (unsigned short)(u >> 16);
}
__device__ inline float bfhi(unsigned u) {           // bf16 in high half
    return __uint_as_float(u & 0xFFFF0000u);
}
__device__ inline float bflo(unsigned u) {           // bf16 in low half
    return __uint_as_float(u << 16);
}
__device__ inline unsigned pack2(float lo, float hi) {
    return ((unsigned)f2bf(hi) << 16) | (unsigned)f2bf(lo);
}
__device__ inline void fma8(float4& a0, float4& a1, float w, uint4 v) {
    a0.x += w * bflo(v.x); a0.y += w * bfhi(v.x);
    a0.z += w * bflo(v.y); a0.w += w * bfhi(v.y);
    a1.x += w * bflo(v.z); a1.y += w * bfhi(v.z);
    a1.z += w * bflo(v.w); a1.w += w * bfhi(v.w);
}

// blocks [0,PB): partition edges into coarse buckets. blocks [PB,PB+CB): x colsum.
__global__ void k_part(const int* __restrict__ row, const int* __restrict__ col,
                       const float* __restrict__ ew, const float* __restrict__ x,
                       int* __restrict__ bcur, uint2* __restrict__ breg,
                       float* __restrict__ gsum, int E, int N) {
    __shared__ int shi[512];   // [0,256)=hist/cursor, [256,512)=chunk base; colsum aliases float
    if ((int)blockIdx.x < PB) {
        int* hist = shi;
        int* base = shi + 256;
        int rng = (E + PB - 1) / PB;
        int e0 = blockIdx.x * rng;
        int e1 = e0 + rng; if (e1 > E) e1 = E;
        hist[threadIdx.x] = 0;
        __syncthreads();
        for (int e = e0 + (int)threadIdx.x; e < e1; e += 256)
            atomicAdd(&hist[(unsigned)col[e] >> 8], 1);
        __syncthreads();
        int h = hist[threadIdx.x];
        if (h) base[threadIdx.x] = atomicAdd(&bcur[threadIdx.x], h);
        __syncthreads();
        hist[threadIdx.x] = 0;   // reuse as block-local cursor
        __syncthreads();
        for (int e = e0 + (int)threadIdx.x; e < e1; e += 256) {
            int c = col[e];
            int b = (unsigned)c >> 8;
            int r = atomicAdd(&hist[b], 1);
            int pos = base[b] + r;
            if (pos < BCAP)
                breg[(size_t)b * BCAP + pos] =
                    make_uint2(((unsigned)f2bf(ew[e]) << 16) | (unsigned)row[e], (unsigned)c);
        }
    } else {
        float* sh = (float*)shi;
        int bid = blockIdx.x - PB;        // 0..CB-1
        int f = threadIdx.x & 127;
        int sub = threadIdx.x >> 7;       // 0/1
        float acc = 0.f;
        for (int n = bid * 2 + sub; n < N; n += CB * 2)
            acc += x[(size_t)n * D + f];
        if (sub) sh[f] = acc;
        __syncthreads();
        if (!sub) atomicAdd(&gsum[f], acc + sh[f]);
    }
}

// blocks [0,GB): group bucket -> slots, cnt, dinv (LDS atomics only).
// blocks [GB,...): init (x copy / mean broadcast / bf16 staging).
__global__ void k_prep(const int* __restrict__ bcur, const uint2* __restrict__ breg,
                       int* __restrict__ cnt, float* __restrict__ dinv,
                       unsigned* __restrict__ slots, const float4* __restrict__ x4,
                       const float* __restrict__ gsum, float4* __restrict__ out4,
                       uint4* __restrict__ xb0, int N, int GB, float invN) {
    __shared__ int shi[512];   // [0,256)=ncur, [256,512)=wsum(float)
    if ((int)blockIdx.x < GB) {
        int* ncur = shi;
        float* wsum = (float*)(shi + 256);
        int b = blockIdx.x;
        ncur[threadIdx.x] = 0;
        wsum[threadIdx.x] = 0.f;
        __syncthreads();
        int cb = bcur[b]; if (cb > BCAP) cb = BCAP;
        const uint2* br = breg + (size_t)b * BCAP;
        for (int i = threadIdx.x; i < cb; i += 256) {
            uint2 ed = br[i];
            int node = (int)ed.y;
            int l = node & 255;
            int r = atomicAdd(&ncur[l], 1);
            if (r < CAP) slots[(size_t)node * CAP + r] = ed.x;
            atomicAdd(&wsum[l], bfhi(ed.x));
        }
        __syncthreads();
        int node = b * 256 + (int)threadIdx.x;
        if (node < N) {
            cnt[node] = ncur[threadIdx.x];
            float v = wsum[threadIdx.x];
            dinv[node] = v > 0.f ? rsqrtf(v) : 0.f;
        }
    } else {
        int t = (blockIdx.x - GB) * 256 + threadIdx.x;
        if (t >= N * 16) return;
        int n = t >> 4;
        int q = t & 15;
        float4 v0 = x4[(size_t)n * 32 + 2 * q];
        float4 v1 = x4[(size_t)n * 32 + 2 * q + 1];
        size_t ob = (size_t)n * OUTC4;
        out4[ob + 2 * q] = v0;
        out4[ob + 2 * q + 1] = v1;
        xb0[(size_t)n * 16 + q] = make_uint4(pack2(v0.x, v0.y), pack2(v0.z, v0.w),
                                             pack2(v1.x, v1.y), pack2(v1.z, v1.w));
        int g = 8 * q;
        out4[ob + 128 + 2 * q] = make_float4(gsum[g] * invN, gsum[g + 1] * invN,
                                             gsum[g + 2] * invN, gsum[g + 3] * invN);
        out4[ob + 129 + 2 * q] = make_float4(gsum[g + 4] * invN, gsum[g + 5] * invN,
                                             gsum[g + 6] * invN, gsum[g + 7] * invN);
    }
}

// pull hop: 16 lanes/node, lane owns 8 bf16 columns. Chunk-8 edge loop for MLP.
// NORM (hop1): w = dinv[dst]*ew*dinv[src] fp32; slot rewritten as bf16(w).
template <bool NORM>
__global__ void k_prop(const int* __restrict__ cnt, unsigned* __restrict__ slots,
                       const float* __restrict__ dinv, const uint4* __restrict__ xin,
                       float4* __restrict__ out4, uint4* __restrict__ xout,
                       int N, int out_off4, int writeb) {
    int t = blockIdx.x * blockDim.x + threadIdx.x;
    int node = t >> 4;
    if (node >= N) return;
    int lane = t & 15;
    int c = cnt[node]; if (c > CAP) c = CAP;
    unsigned* s = slots + (size_t)node * CAP;
    float dd = NORM ? dinv[node] : 0.f;
    float4 a0 = make_float4(0.f, 0.f, 0.f, 0.f);
    float4 a1 = make_float4(0.f, 0.f, 0.f, 0.f);
    int i = 0;
    for (; i + CH <= c; i += CH) {
        unsigned sl[CH]; float w[CH]; uint4 v[CH];
#pragma unroll
        for (int j = 0; j < CH; j++) sl[j] = s[i + j];
#pragma unroll
        for (int j = 0; j < CH; j++)
            w[j] = NORM ? dd * bfhi(sl[j]) * dinv[sl[j] & 0xFFFFu] : bfhi(sl[j]);
        if (NORM && lane == 0) {
#pragma unroll
            for (int j = 0; j < CH; j++)
                s[i + j] = ((unsigned)f2bf(w[j]) << 16) | (sl[j] & 0xFFFFu);
        }
#pragma unroll
        for (int j = 0; j < CH; j++) v[j] = xin[(size_t)(sl[j] & 0xFFFFu) * 16 + lane];
#pragma unroll
        for (int j = 0; j < CH; j++) fma8(a0, a1, w[j], v[j]);
    }
    if (i < c) {  // predicated tail chunk; clamped dup addresses are L1-hits
        unsigned sl[CH]; float w[CH]; uint4 v[CH];
#pragma unroll
        for (int j = 0; j < CH; j++) {
            int idx = (i + j < c) ? i + j : c - 1;
            sl[j] = s[idx];
        }
#pragma unroll
        for (int j = 0; j < CH; j++) {
            float ww = NORM ? dd * bfhi(sl[j]) * dinv[sl[j] & 0xFFFFu] : bfhi(sl[j]);
            w[j] = (i + j < c) ? ww : 0.f;
        }
        if (NORM && lane == 0) {
#pragma unroll
            for (int j = 0; j < CH; j++)
                if (i + j < c) s[i + j] = ((unsigned)f2bf(w[j]) << 16) | (sl[j] & 0xFFFFu);
        }
#pragma unroll
        for (int j = 0; j < CH; j++) v[j] = xin[(size_t)(sl[j] & 0xFFFFu) * 16 + lane];
#pragma unroll
        for (int j = 0; j < CH; j++) fma8(a0, a1, w[j], v[j]);
    }
    size_t ob = (size_t)node * OUTC4 + out_off4 + 2 * lane;
    out4[ob] = a0;
    out4[ob + 1] = a1;
    if (writeb)
        xout[(size_t)node * 16 + lane] =
            make_uint4(pack2(a0.x, a0.y), pack2(a0.z, a0.w),
                       pack2(a1.x, a1.y), pack2(a1.z, a1.w));
}

extern "C" void kernel_launch(void* const* d_in, const int* in_sizes, int n_in,
                              void* d_out, int out_size, void* d_ws, size_t ws_size,
                              hipStream_t stream) {
    const float* x = (const float*)d_in[0];
    const int* ei = (const int*)d_in[1];   // int32 per harness convention
    const float* ew = (const float*)d_in[2];
    float* out = (float*)d_out;

    int N = in_sizes[0] / D;
    int E = in_sizes[2];
    const int* row = ei;        // source
    const int* colp = ei + E;   // target

    // ws: [bcur 256 i | gsum 128 f | cnt N i | dinv N f | slots N*CAP u32 |
    //      breg PB*BCAP uint2 | xb0 N*16 uint4 | xb1 ...]
    int* bcur = (int*)d_ws;
    float* gsum = (float*)(bcur + 256);
    int* cnt = (int*)(gsum + 128);
    float* dinv = (float*)(cnt + N);
    unsigned* slots = (unsigned*)(dinv + N);
    uint2* breg = (uint2*)(slots + (size_t)N * CAP);
    uint4* xb0 = (uint4*)(breg + (size_t)PB * BCAP);
    uint4* xb1 = xb0 + (size_t)N * 16;

    hipMemsetAsync(d_ws, 0, 384 * sizeof(int), stream);   // bcur + gsum only

    k_part<<<PB + CB, 256, 0, stream>>>(row, colp, ew, x, bcur, breg, gsum, E, N);

    int GB = (N + 255) / 256;                    // grouping blocks (one per bucket)
    int IB = (N * 16 + 255) / 256;               // init blocks
    k_prep<<<GB + IB, 256, 0, stream>>>(bcur, breg, cnt, dinv, slots, (const float4*)x,
                                        gsum, (float4*)out, xb0, N, GB, 1.f / (float)N);

    int pblocks = (N * 16 + 255) / 256;
    // hop1 (fused norm): xb0 -> out[:,128:256] + xb1
    k_prop<true><<<pblocks, 256, 0, stream>>>(cnt, slots, dinv, xb0, (float4*)out, xb1, N, 32, 1);
    // hop2: xb1 -> out[:,256:384] + xb0
    k_prop<false><<<pblocks, 256, 0, stream>>>(cnt, slots, dinv, xb1, (float4*)out, xb0, N, 64, 1);
    // hop3: xb0 -> out[:,384:512]
    k_prop<false><<<pblocks, 256, 0, stream>>>(cnt, slots, dinv, xb0, (float4*)out, xb1, N, 96, 0);
}